// Round 11
// baseline (115.582 us; speedup 1.0000x reference)
//
#include <hip/hip_runtime.h>
#include <stdint.h>

// Segmented kNN graph: M=65536 pts, D=16, 64 segments x 1024 pts, K=16.
// Output: int32 src[M*16] then int32 dst[M*16].
//
// v11 = v9/v10 quad-min arithmetic, fp8-staged for tail-free 7 waves/EU.
// Post-mortem r10: v10's 42.25KB LDS -> 3 blocks/CU vs grid 4/CU = 256-block
// tail at 1 block/CU, canceling the concurrency gain (latency-bound blocks
// have ~fixed critical path). Fix: fp8 e4m3 coords (16KB) -> LDS 22.6KB ->
// 7 blocks/CU; 32-query blocks, grid 2048, smooth backfill (no hard tail).
// mfma_f32_16x16x32_fp8_fp8, K-dims 16..31 zero-padded via LDS zero slot
// (lanes g>=2); C/D layout shape-determined -> quad ownership unchanged.
// A = fp8(-2c), B = fp8(q), C = 128+|c|^2 (f32) -> acc = key directly.
// Repair partner dots from GLOBAL f32 coords (L2-hot, no fp8 unpack).

#define L_SEG 1024
#define M_PTS 65536

typedef float f32x4 __attribute__((ext_vector_type(4)));

// LDS layout (bytes)
#define SC_OFF     0        // fp8(-2c) [1024][16]
#define SSQ_OFF    16384    // f32 |c|^2+128 [1024]
#define SQF8_OFF   20480    // fp8(q) [32][16]
#define ZOFF       20992    // 16B zeros (K-pad)
#define SMERGE_OFF 21008    // u32 [32][16]
#define LDS_BYTES  23056

__device__ __forceinline__ uint32_t umn(uint32_t a, uint32_t b) { return a < b ? a : b; }
__device__ __forceinline__ uint32_t umx(uint32_t a, uint32_t b) { return a > b ? a : b; }

#define CE(arr, i, p) { uint32_t lo = umn(arr[i], arr[p]); uint32_t hi = umx(arr[i], arr[p]); arr[i] = lo; arr[p] = hi; }

__device__ __forceinline__ void clean16(uint32_t* A) {
    #pragma unroll
    for (int j = 8; j > 0; j >>= 1) {
        #pragma unroll
        for (int i = 0; i < 16; ++i) {
            int p = i ^ j;
            if (p > i) CE(A, i, p);
        }
    }
}

// Batcher odd-even mergesort-16, ascending (63 CEs)
__device__ __forceinline__ void sort16(uint32_t* B) {
    #pragma unroll
    for (int p = 1; p < 16; p <<= 1) {
        #pragma unroll
        for (int k = p; k >= 1; k >>= 1) {
            #pragma unroll
            for (int j = (k & (p - 1)); j + k < 16; j += 2 * k) {
                #pragma unroll
                for (int i = 0; i <= ((k - 1 < 15 - j - k) ? k - 1 : 15 - j - k); ++i) {
                    if ((i + j) / (2 * p) == (i + j + k) / (2 * p)) CE(B, i + j, i + j + k);
                }
            }
        }
    }
}

__device__ __forceinline__ void keep16(uint32_t* A, const uint32_t* S) {
    #pragma unroll
    for (int i = 0; i < 16; ++i) A[i] = umn(A[i], S[15 - i]);
    clean16(A);
}

// cross-lane merges over g (xor 16 then 32): disjoint contents per lane
__device__ __forceinline__ void mergeg(uint32_t* A) {
    #pragma unroll
    for (int m = 16; m <= 32; m <<= 1) {
        uint32_t P[16];
        #pragma unroll
        for (int i = 0; i < 16; ++i) P[i] = (uint32_t)__shfl_xor((int)A[15 - i], m, 64);
        #pragma unroll
        for (int i = 0; i < 16; ++i) A[i] = umn(A[i], P[i]);
        clean16(A);
    }
}

__device__ __forceinline__ uint32_t sel4(const uint32_t* A, int g, int v) {
    uint32_t t01 = (g & 1) ? A[4 + v]  : A[v];
    uint32_t t23 = (g & 1) ? A[12 + v] : A[8 + v];
    return (g & 2) ? t23 : t01;
}

__global__ __launch_bounds__(256, 7) void knn_v11_kernel(const float* __restrict__ x,
                                                         int* __restrict__ out) {
    __shared__ __attribute__((aligned(16))) char smem[LDS_BYTES];

    const int tid   = threadIdx.x;
    const int b     = blockIdx.x;
    // bijective over 2048: seg = (b&7)*8 + (b>>8)  [XCD-sliced], panel = (b>>3)&31
    const int seg   = (b & 7) * 8 + (b >> 8);
    const int panel = (b >> 3) & 31;
    const int qbase = panel * 32;
    const float* xseg = x + (size_t)seg * (L_SEG * 16);
    const f32x4* gx4  = (const f32x4*)xseg;

    // ---- phase 1: stage everything (one barrier) ----
    // coords: fp8(-2c), dword (4 dims) per iter; coalesced global, stride-4B LDS
    #pragma unroll
    for (int i = 0; i < 16; ++i) {
        const int idx = tid + 256 * i;        // cand = idx>>2, dimquad = idx&3
        f32x4 v = gx4[idx];
        int lo = __builtin_amdgcn_cvt_pk_fp8_f32(-2.0f * v[0], -2.0f * v[1], 0, false);
        int fl = __builtin_amdgcn_cvt_pk_fp8_f32(-2.0f * v[2], -2.0f * v[3], lo, true);
        *(int*)(smem + SC_OFF + (size_t)idx * 4) = fl;
    }
    // norms: 128 + |c|^2 (f32, from global)
    {
        const int c0 = tid << 2;
        #pragma unroll
        for (int c = 0; c < 4; ++c) {
            float s = 128.0f;
            #pragma unroll
            for (int d = 0; d < 4; ++d) {
                f32x4 v = gx4[(c0 + c) * 4 + d];
                s = __builtin_fmaf(v[0], v[0], s);
                s = __builtin_fmaf(v[1], v[1], s);
                s = __builtin_fmaf(v[2], v[2], s);
                s = __builtin_fmaf(v[3], v[3], s);
            }
            ((float*)(smem + SSQ_OFF))[c0 + c] = s;
        }
    }
    // queries: fp8(q), unscaled
    if (tid < 32) {
        const f32x4* qr = gx4 + (size_t)(qbase + tid) * 4;
        #pragma unroll
        for (int d = 0; d < 4; ++d) {
            f32x4 v = qr[d];
            int lo = __builtin_amdgcn_cvt_pk_fp8_f32(v[0], v[1], 0, false);
            int fl = __builtin_amdgcn_cvt_pk_fp8_f32(v[2], v[3], lo, true);
            *(int*)(smem + SQF8_OFF + (size_t)tid * 16 + d * 4) = fl;
        }
    }
    if (tid < 4) *(int*)(smem + ZOFF + tid * 4) = 0;
    __syncthreads();

    const int lane  = tid & 63;
    const int w     = tid >> 6;   // 0..3
    const int qg    = w & 1;      // query group of 16
    const int half  = w >> 1;     // candidate half (512 cands)
    const int g     = lane >> 4;  // C/D row group: owns cands base+4g..4g+3
    const int col   = lane & 15;  // query column / A row
    const int qloc  = qg * 16 + col;        // block-local query 0..31
    const int qglob = seg * L_SEG + qbase + qloc;

    // B fragment: fp8 q bytes [8g..8g+8), zero for g>=2 (K pad)
    const char* baddr = (g < 2) ? (smem + SQF8_OFF + (size_t)qloc * 16 + g * 8)
                                : (smem + ZOFF);
    const long bfrag = *(const long*)baddr;

    // A fragment stream: fp8(-2c) bytes of cand row, zero for g>=2
    const char* abase = (g < 2) ? (smem + SC_OFF + (size_t)col * 16 + g * 8)
                                : (smem + ZOFF);
    const int   astep = (g < 2) ? 256 : 0;   // bytes per 16-cand tile

    uint32_t A[16];
    #pragma unroll
    for (int i = 0; i < 16; ++i) A[i] = 0xFFFFFFFFu;

    const float* ssq = (const float*)(smem + SSQ_OFF);
    const uint32_t vg4 = (uint32_t)(g << 2);
    const int hb = half * 512;
    const char* aptr = abase + (size_t)hb * 16 * (astep ? 1 : 0);

    #pragma unroll
    for (int chain = 0; chain < 2; ++chain) {
        uint32_t P[16];
        const int cb0 = hb + chain * 256;
        #pragma unroll
        for (int t = 0; t < 16; ++t) {
            const int tb = cb0 + t * 16;
            const long a = *(const long*)aptr;
            aptr += astep;
            const f32x4 sq = *(const f32x4*)(ssq + tb + g * 4);
            // acc[v] = 128 + |c|^2 - 2<c~,q~>, cand = tb + 4g + v (one quad)
            f32x4 acc = __builtin_amdgcn_mfma_f32_16x16x32_fp8_fp8(a, bfrag, sq, 0, 0, 0);
            const uint32_t ib = (uint32_t)tb + vg4;
            uint32_t k0 = (__float_as_uint(acc[0]) & 0xFFFFFC00u) | ib;
            uint32_t k1 = (__float_as_uint(acc[1]) & 0xFFFFFC00u) | (ib + 1u);
            uint32_t k2 = (__float_as_uint(acc[2]) & 0xFFFFFC00u) | (ib + 2u);
            uint32_t k3 = (__float_as_uint(acc[3]) & 0xFFFFFC00u) | (ib + 3u);
            P[t] = umn(umn(k0, k1), umn(k2, k3));
        }
        sort16(P);
        keep16(A, P);
    }

    mergeg(A);  // all 4 g-lanes: sorted top-16 quad-mins of this half

    // ---- cross-half merge via LDS ----
    uint32_t* sm = (uint32_t*)(smem + SMERGE_OFF);
    if (half == 1) {
        #pragma unroll
        for (int v = 0; v < 4; ++v) sm[qloc * 16 + g * 4 + v] = A[g * 4 + v];
    }
    __syncthreads();
    if (half == 1) return;
    {
        uint32_t Q[16];
        #pragma unroll
        for (int i = 0; i < 16; ++i) Q[i] = sm[qloc * 16 + i];
        keep16(A, Q);
    }

    // ---- repair: 3 quad-partners per winner, f32 dots from global (L2-hot) ----
    f32x4 qf[4];
    {
        const f32x4* qr = gx4 + (size_t)(qbase + qloc) * 4;
        #pragma unroll
        for (int d = 0; d < 4; ++d) qf[d] = qr[d];
    }
    uint32_t R[16];
    #pragma unroll
    for (int v = 0; v < 4; ++v) {
        const uint32_t win = sel4(A, g, v);
        const uint32_t wi  = win & 1023u;
        const uint32_t qb2 = wi & ~3u;
        const uint32_t wo  = wi & 3u;
        #pragma unroll
        for (int k = 0; k < 3; ++k) {
            const uint32_t o    = (uint32_t)k + (((uint32_t)k >= wo) ? 1u : 0u);
            const uint32_t pidx = qb2 + o;
            const f32x4* cr = gx4 + (size_t)pidx * 4;
            float s = 0.0f;
            #pragma unroll
            for (int d = 0; d < 4; ++d) {
                f32x4 cv = cr[d];
                s = __builtin_fmaf(cv[0], qf[d][0], s);
                s = __builtin_fmaf(cv[1], qf[d][1], s);
                s = __builtin_fmaf(cv[2], qf[d][2], s);
                s = __builtin_fmaf(cv[3], qf[d][3], s);
            }
            const float val = __builtin_fmaf(s, -2.0f, ssq[pidx]);  // 128+|c|^2-2<c,q>
            R[v * 3 + k] = (__float_as_uint(val) & 0xFFFFFC00u) | pidx;
        }
    }
    #pragma unroll
    for (int i = 12; i < 16; ++i) R[i] = 0xFFFFFFFFu;
    sort16(R);
    mergeg(R);       // 48 partners across g-lanes -> lowest 16, all lanes equal
    keep16(A, R);    // exact top-16 of winners ∪ partners

    // ---- epilogue ----
    const int base = seg * L_SEG;
    const int q    = qglob;
    int4 sv;
    sv.x = base + (int)(sel4(A, g, 0) & 1023u);
    sv.y = base + (int)(sel4(A, g, 1) & 1023u);
    sv.z = base + (int)(sel4(A, g, 2) & 1023u);
    sv.w = base + (int)(sel4(A, g, 3) & 1023u);
    ((int4*)out)[(size_t)q * 4 + g] = sv;
    ((int4*)out)[(size_t)M_PTS * 4 + (size_t)q * 4 + g] = make_int4(q, q, q, q);
}

extern "C" void kernel_launch(void* const* d_in, const int* in_sizes, int n_in,
                              void* d_out, int out_size, void* d_ws, size_t ws_size,
                              hipStream_t stream) {
    const float* x = (const float*)d_in[0];
    // d_in[1] = segs (int64, all 1024) — static per problem setup, unused.
    int* out = (int*)d_out;
    (void)d_ws; (void)ws_size;
    knn_v11_kernel<<<dim3(2048), dim3(256), 0, stream>>>(x, out);
}

// Round 12
// 109.255 us; speedup vs baseline: 1.0579x; 1.0579x over previous
//
#include <hip/hip_runtime.h>
#include <stdint.h>

// Segmented kNN graph: M=65536 pts, D=16, 64 segments x 1024 pts, K=16.
// Output: int32 src[M*16] then int32 dst[M*16].
//
// v12: exact single-generation co-residency: 8 blocks/CU x 256 thr =
// 32 waves/CU, grid 2048 = exactly 8 blocks/CU -> zero tail (r10's bug),
// LDS exactly 20480 B (fp8(-2c) 16K + f32 norms 4K), launch_bounds(256,8)
// with repair restructured to fit 64 VGPRs (r11 spilled: VGPR 36, +22MB
// scratch writes). B-frags packed in-register from global (no query LDS);
// K-pad lanes g>=2 carry zero B => their A values are inert (no zero slot).
// Merge/winner buffers overlay the norm region post-main-loop; repair
// folds the norm: key = 128 + sum c*(c-2q) from global f32 (L2-hot).
// Selection: quad-min pre-reduction (exact w/ 3-partner repair), Batcher
// sort-16, bitonic merges. Keys: f32 bits | 10-bit idx (order-preserving).

#define L_SEG 1024
#define M_PTS 65536

typedef float f32x4 __attribute__((ext_vector_type(4)));

#define SC_OFF    0        // fp8(-2c) [1024][16] = 16384 B
#define SSQ_OFF   16384    // f32 128+|c|^2 [1024] = 4096 B (overlaid after main loop)
#define SMG_OFF   16384    // overlay: u32 [32][16] merge/winner buf (2048 B)
#define LDS_BYTES 20480

__device__ __forceinline__ uint32_t umn(uint32_t a, uint32_t b) { return a < b ? a : b; }
__device__ __forceinline__ uint32_t umx(uint32_t a, uint32_t b) { return a > b ? a : b; }

#define CE(arr, i, p) { uint32_t lo = umn(arr[i], arr[p]); uint32_t hi = umx(arr[i], arr[p]); arr[i] = lo; arr[p] = hi; }

__device__ __forceinline__ void clean16(uint32_t* A) {
    #pragma unroll
    for (int j = 8; j > 0; j >>= 1) {
        #pragma unroll
        for (int i = 0; i < 16; ++i) {
            int p = i ^ j;
            if (p > i) CE(A, i, p);
        }
    }
}

// Batcher odd-even mergesort-16, ascending (63 CEs)
__device__ __forceinline__ void sort16(uint32_t* B) {
    #pragma unroll
    for (int p = 1; p < 16; p <<= 1) {
        #pragma unroll
        for (int k = p; k >= 1; k >>= 1) {
            #pragma unroll
            for (int j = (k & (p - 1)); j + k < 16; j += 2 * k) {
                #pragma unroll
                for (int i = 0; i <= ((k - 1 < 15 - j - k) ? k - 1 : 15 - j - k); ++i) {
                    if ((i + j) / (2 * p) == (i + j + k) / (2 * p)) CE(B, i + j, i + j + k);
                }
            }
        }
    }
}

__device__ __forceinline__ void keep16(uint32_t* A, const uint32_t* S) {
    #pragma unroll
    for (int i = 0; i < 16; ++i) A[i] = umn(A[i], S[15 - i]);
    clean16(A);
}

// cross-lane merges over g (xor 16 then 32): disjoint contents per lane
__device__ __forceinline__ void mergeg(uint32_t* A) {
    #pragma unroll
    for (int m = 16; m <= 32; m <<= 1) {
        uint32_t P[16];
        #pragma unroll
        for (int i = 0; i < 16; ++i) P[i] = (uint32_t)__shfl_xor((int)A[15 - i], m, 64);
        #pragma unroll
        for (int i = 0; i < 16; ++i) A[i] = umn(A[i], P[i]);
        clean16(A);
    }
}

__device__ __forceinline__ uint32_t sel4(const uint32_t* A, int g, int v) {
    uint32_t t01 = (g & 1) ? A[4 + v]  : A[v];
    uint32_t t23 = (g & 1) ? A[12 + v] : A[8 + v];
    return (g & 2) ? t23 : t01;
}

__global__ __launch_bounds__(256, 8) void knn_v12_kernel(const float* __restrict__ x,
                                                         int* __restrict__ out) {
    __shared__ __attribute__((aligned(16))) char smem[LDS_BYTES];

    const int tid   = threadIdx.x;
    const int b     = blockIdx.x;
    // bijective over 2048: bits 0-2 XCD slice, 3-7 panel, 8-10 seg-within-XCD
    const int seg   = (b & 7) * 8 + (b >> 8);
    const int panel = (b >> 3) & 31;
    const int qbase = panel * 32;
    const f32x4* gx4 = (const f32x4*)(x + (size_t)seg * (L_SEG * 16));

    float* ssq = (float*)(smem + SSQ_OFF);

    // ---- stage fp8(-2c) coords + fused norms (one pass over global) ----
    #pragma unroll
    for (int i = 0; i < 16; ++i) {
        const int idx = tid + 256 * i;        // dword idx; cand = idx>>2
        f32x4 v = gx4[idx];
        int w0 = __builtin_amdgcn_cvt_pk_fp8_f32(-2.0f * v[0], -2.0f * v[1], 0, false);
        w0     = __builtin_amdgcn_cvt_pk_fp8_f32(-2.0f * v[2], -2.0f * v[3], w0, true);
        *(int*)(smem + SC_OFF + (size_t)idx * 4) = w0;
        float ps = v[0] * v[0];
        ps = __builtin_fmaf(v[1], v[1], ps);
        ps = __builtin_fmaf(v[2], v[2], ps);
        ps = __builtin_fmaf(v[3], v[3], ps);
        // lanes tid^1, tid^2 hold the other dim-quads of the same candidate
        ps += __shfl_xor(ps, 1, 64);
        ps += __shfl_xor(ps, 2, 64);
        if ((tid & 3) == 0) ssq[idx >> 2] = ps + 128.0f;
    }
    __syncthreads();

    const int lane  = tid & 63;
    const int w     = tid >> 6;   // 0..3
    const int qg    = w & 1;      // query group of 16
    const int half  = w >> 1;     // candidate half (512 cands)
    const int g     = lane >> 4;  // C/D row group: owns cands base+4g..4g+3
    const int col   = lane & 15;  // query column / A row
    const int qloc  = qg * 16 + col;
    const int qglob = seg * L_SEG + qbase + qloc;

    // ---- B fragment in-register: fp8(q) dims 8g..8g+7; zero for g>=2 (K pad).
    // Zero B makes the g>=2 lanes' A values inert (summed against 0).
    long bfrag = 0;
    if (g < 2) {
        const f32x4* qr = gx4 + (size_t)(qbase + qloc) * 4 + g * 2;
        f32x4 v0 = qr[0], v1 = qr[1];
        int w0 = __builtin_amdgcn_cvt_pk_fp8_f32(v0[0], v0[1], 0, false);
        w0     = __builtin_amdgcn_cvt_pk_fp8_f32(v0[2], v0[3], w0, true);
        int w1 = __builtin_amdgcn_cvt_pk_fp8_f32(v1[0], v1[1], 0, false);
        w1     = __builtin_amdgcn_cvt_pk_fp8_f32(v1[2], v1[3], w1, true);
        bfrag = (long)(uint32_t)w0 | (((long)w1) << 32);
    }

    // A-frag address: g>=2 lanes alias g-2 (values inert)
    const char* ap = smem + SC_OFF + (size_t)col * 16 + (g & 1) * 8;
    const uint32_t vg4 = (uint32_t)(g << 2);
    const int hb = half * 512;

    uint32_t A[16], P[16];
    #pragma unroll
    for (int chain = 0; chain < 2; ++chain) {
        uint32_t* D = chain ? P : A;
        #pragma unroll
        for (int t = 0; t < 16; ++t) {
            const int tb = hb + chain * 256 + t * 16;
            const long a = *(const long*)(ap + (size_t)tb * 16);
            const f32x4 sq = *(const f32x4*)(ssq + tb + g * 4);
            // acc[v] = 128 + |c|^2 - 2<c~,q~>, cand = tb + 4g + v (one quad)
            f32x4 acc = __builtin_amdgcn_mfma_f32_16x16x32_fp8_fp8(a, bfrag, sq, 0, 0, 0);
            const uint32_t ib = (uint32_t)tb + vg4;
            uint32_t k0 = (__float_as_uint(acc[0]) & 0xFFFFFC00u) | ib;
            uint32_t k1 = (__float_as_uint(acc[1]) & 0xFFFFFC00u) | (ib + 1u);
            uint32_t k2 = (__float_as_uint(acc[2]) & 0xFFFFFC00u) | (ib + 2u);
            uint32_t k3 = (__float_as_uint(acc[3]) & 0xFFFFFC00u) | (ib + 3u);
            D[t] = umn(umn(k0, k1), umn(k2, k3));
        }
        sort16(D);
    }
    keep16(A, P);
    mergeg(A);  // all 4 g-lanes: identical sorted top-16 quad-mins of this half

    // ---- cross-half merge; merge buffer overlays the norm region ----
    uint32_t* sm = (uint32_t*)(smem + SMG_OFF);
    __syncthreads();                  // everyone done reading coords/norms
    if (half == 1) {
        #pragma unroll
        for (int v = 0; v < 4; ++v) sm[qloc * 16 + g * 4 + v] = sel4(A, g, v);
    }
    __syncthreads();
    if (half == 1) return;

    {
        uint32_t Q[16];
        #pragma unroll
        for (int i = 0; i < 16; ++i) Q[i] = sm[qloc * 16 + i];
        keep16(A, Q);
    }

    // winners: lane g owns A[4g..4g+3]; stash full A to LDS (frees regs in repair)
    uint32_t win[4];
    #pragma unroll
    for (int v = 0; v < 4; ++v) {
        win[v] = sel4(A, g, v);
        sm[qloc * 16 + g * 4 + v] = win[v];   // wave-lockstep write, read back later
    }

    // ---- repair: 3 quad-partners per winner, f32 from global, fused norm ----
    const f32x4* qr = gx4 + (size_t)(qbase + qloc) * 4;
    const f32x4 qf0 = qr[0], qf1 = qr[1], qf2 = qr[2], qf3 = qr[3];
    uint32_t R[16];
    #pragma unroll
    for (int v = 0; v < 4; ++v) {
        const uint32_t wi  = win[v] & 1023u;
        const uint32_t qb2 = wi & ~3u;
        const uint32_t wo  = wi & 3u;
        #pragma unroll
        for (int k = 0; k < 3; ++k) {
            const uint32_t o    = (uint32_t)k + (((uint32_t)k >= wo) ? 1u : 0u);
            const uint32_t pidx = qb2 + o;
            const f32x4* cr = gx4 + (size_t)pidx * 4;
            float s = 128.0f;
            #pragma unroll
            for (int d = 0; d < 4; ++d) {
                f32x4 cv = cr[d];
                f32x4 qv = (d == 0) ? qf0 : (d == 1) ? qf1 : (d == 2) ? qf2 : qf3;
                #pragma unroll
                for (int e = 0; e < 4; ++e) {
                    float t = __builtin_fmaf(qv[e], -2.0f, cv[e]);  // c - 2q
                    s = __builtin_fmaf(cv[e], t, s);                // += c*(c-2q)
                }
            }
            R[v * 3 + k] = (__float_as_uint(s) & 0xFFFFFC00u) | pidx;
        }
    }
    #pragma unroll
    for (int i = 12; i < 16; ++i) R[i] = 0xFFFFFFFFu;
    sort16(R);
    mergeg(R);       // 48 partners across g-lanes -> lowest 16, all lanes equal

    // reload winners (A) and final keep-16
    uint32_t A2[16];
    #pragma unroll
    for (int i = 0; i < 16; ++i) A2[i] = sm[qloc * 16 + i];
    keep16(A2, R);

    // ---- epilogue: lane (g,col) writes int4 #g of src and dst ----
    const int base = seg * L_SEG;
    const int q    = qglob;
    int4 sv;
    sv.x = base + (int)(sel4(A2, g, 0) & 1023u);
    sv.y = base + (int)(sel4(A2, g, 1) & 1023u);
    sv.z = base + (int)(sel4(A2, g, 2) & 1023u);
    sv.w = base + (int)(sel4(A2, g, 3) & 1023u);
    ((int4*)out)[(size_t)q * 4 + g] = sv;
    ((int4*)out)[(size_t)M_PTS * 4 + (size_t)q * 4 + g] = make_int4(q, q, q, q);
}

extern "C" void kernel_launch(void* const* d_in, const int* in_sizes, int n_in,
                              void* d_out, int out_size, void* d_ws, size_t ws_size,
                              hipStream_t stream) {
    const float* x = (const float*)d_in[0];
    // d_in[1] = segs (int64, all 1024) — static per problem setup, unused.
    int* out = (int*)d_out;
    (void)d_ws; (void)ws_size;
    knn_v12_kernel<<<dim3(2048), dim3(256), 0, stream>>>(x, out);
}

// Round 13
// 101.994 us; speedup vs baseline: 1.1332x; 1.0712x over previous
//
#include <hip/hip_runtime.h>
#include <stdint.h>

// Segmented kNN graph: M=65536 pts, D=16, 64 segments x 1024 pts, K=16.
// Output: int32 src[M*16] then int32 dst[M*16].
//
// v13 = v12 with the toxic launch bound removed. Evidence r7/r11/r12 (3x):
// any bound capping VGPR<=64 makes the allocator collapse to 32 regs and
// spill the sort arrays (WRITE +38MB scratch, VALUBusy ~34%). (256,4)
// builds allocate 52 VGPRs naturally (v5/v6) — already under the 64-VGPR
// threshold for 8 waves/SIMD (m69: waves halve at 64/128/256). LDS exactly
// 20480B (fp8(-2c) 16K + f32 norms 4K, merge buf overlaid) -> 8 blocks/CU;
// grid 2048 = exactly 8/CU, zero tail, one generation = 32 waves/CU.
// Arithmetic unchanged from v12: mfma_f32_16x16x32_fp8_fp8 (K-pad lanes
// g>=2 carry zero B => their A garbage is inert), C operand = 128+|c|^2,
// quad-min pre-reduction (exact w/ 3-partner repair from global f32),
// Batcher sort-16 + bitonic merges, keys = f32 bits | 10-bit idx.

#define L_SEG 1024
#define M_PTS 65536

typedef float f32x4 __attribute__((ext_vector_type(4)));

#define SC_OFF    0        // fp8(-2c) [1024][16] = 16384 B
#define SSQ_OFF   16384    // f32 128+|c|^2 [1024] = 4096 B (overlaid after main loop)
#define SMG_OFF   16384    // overlay: u32 [32][16] merge/winner buf (2048 B)
#define LDS_BYTES 20480

__device__ __forceinline__ uint32_t umn(uint32_t a, uint32_t b) { return a < b ? a : b; }
__device__ __forceinline__ uint32_t umx(uint32_t a, uint32_t b) { return a > b ? a : b; }

#define CE(arr, i, p) { uint32_t lo = umn(arr[i], arr[p]); uint32_t hi = umx(arr[i], arr[p]); arr[i] = lo; arr[p] = hi; }

__device__ __forceinline__ void clean16(uint32_t* A) {
    #pragma unroll
    for (int j = 8; j > 0; j >>= 1) {
        #pragma unroll
        for (int i = 0; i < 16; ++i) {
            int p = i ^ j;
            if (p > i) CE(A, i, p);
        }
    }
}

// Batcher odd-even mergesort-16, ascending (63 CEs)
__device__ __forceinline__ void sort16(uint32_t* B) {
    #pragma unroll
    for (int p = 1; p < 16; p <<= 1) {
        #pragma unroll
        for (int k = p; k >= 1; k >>= 1) {
            #pragma unroll
            for (int j = (k & (p - 1)); j + k < 16; j += 2 * k) {
                #pragma unroll
                for (int i = 0; i <= ((k - 1 < 15 - j - k) ? k - 1 : 15 - j - k); ++i) {
                    if ((i + j) / (2 * p) == (i + j + k) / (2 * p)) CE(B, i + j, i + j + k);
                }
            }
        }
    }
}

__device__ __forceinline__ void keep16(uint32_t* A, const uint32_t* S) {
    #pragma unroll
    for (int i = 0; i < 16; ++i) A[i] = umn(A[i], S[15 - i]);
    clean16(A);
}

// cross-lane merges over g (xor 16 then 32): disjoint contents per lane
__device__ __forceinline__ void mergeg(uint32_t* A) {
    #pragma unroll
    for (int m = 16; m <= 32; m <<= 1) {
        uint32_t P[16];
        #pragma unroll
        for (int i = 0; i < 16; ++i) P[i] = (uint32_t)__shfl_xor((int)A[15 - i], m, 64);
        #pragma unroll
        for (int i = 0; i < 16; ++i) A[i] = umn(A[i], P[i]);
        clean16(A);
    }
}

__device__ __forceinline__ uint32_t sel4(const uint32_t* A, int g, int v) {
    uint32_t t01 = (g & 1) ? A[4 + v]  : A[v];
    uint32_t t23 = (g & 1) ? A[12 + v] : A[8 + v];
    return (g & 2) ? t23 : t01;
}

__global__ __launch_bounds__(256, 4) void knn_v13_kernel(const float* __restrict__ x,
                                                         int* __restrict__ out) {
    __shared__ __attribute__((aligned(16))) char smem[LDS_BYTES];

    const int tid   = threadIdx.x;
    const int b     = blockIdx.x;
    // bijective over 2048: bits 0-2 XCD slice, 3-7 panel, 8-10 seg-within-XCD
    const int seg   = (b & 7) * 8 + (b >> 8);
    const int panel = (b >> 3) & 31;
    const int qbase = panel * 32;
    const f32x4* gx4 = (const f32x4*)(x + (size_t)seg * (L_SEG * 16));

    float* ssq = (float*)(smem + SSQ_OFF);

    // ---- stage fp8(-2c) coords + fused norms (one pass over global) ----
    #pragma unroll
    for (int i = 0; i < 16; ++i) {
        const int idx = tid + 256 * i;        // dword idx; cand = idx>>2
        f32x4 v = gx4[idx];
        int w0 = __builtin_amdgcn_cvt_pk_fp8_f32(-2.0f * v[0], -2.0f * v[1], 0, false);
        w0     = __builtin_amdgcn_cvt_pk_fp8_f32(-2.0f * v[2], -2.0f * v[3], w0, true);
        *(int*)(smem + SC_OFF + (size_t)idx * 4) = w0;
        float ps = v[0] * v[0];
        ps = __builtin_fmaf(v[1], v[1], ps);
        ps = __builtin_fmaf(v[2], v[2], ps);
        ps = __builtin_fmaf(v[3], v[3], ps);
        // lanes tid^1, tid^2 hold the other dim-quads of the same candidate
        ps += __shfl_xor(ps, 1, 64);
        ps += __shfl_xor(ps, 2, 64);
        if ((tid & 3) == 0) ssq[idx >> 2] = ps + 128.0f;
    }
    __syncthreads();

    const int lane  = tid & 63;
    const int w     = tid >> 6;   // 0..3
    const int qg    = w & 1;      // query group of 16
    const int half  = w >> 1;     // candidate half (512 cands)
    const int g     = lane >> 4;  // C/D row group: owns cands base+4g..4g+3
    const int col   = lane & 15;  // query column / A row
    const int qloc  = qg * 16 + col;
    const int qglob = seg * L_SEG + qbase + qloc;

    // ---- B fragment in-register: fp8(q) dims 8g..8g+7; zero for g>=2 (K pad).
    // Zero B makes the g>=2 lanes' A values inert (summed against 0).
    long bfrag = 0;
    if (g < 2) {
        const f32x4* qr = gx4 + (size_t)(qbase + qloc) * 4 + g * 2;
        f32x4 v0 = qr[0], v1 = qr[1];
        int w0 = __builtin_amdgcn_cvt_pk_fp8_f32(v0[0], v0[1], 0, false);
        w0     = __builtin_amdgcn_cvt_pk_fp8_f32(v0[2], v0[3], w0, true);
        int w1 = __builtin_amdgcn_cvt_pk_fp8_f32(v1[0], v1[1], 0, false);
        w1     = __builtin_amdgcn_cvt_pk_fp8_f32(v1[2], v1[3], w1, true);
        bfrag = (long)(uint32_t)w0 | (((long)w1) << 32);
    }

    // A-frag address: g>=2 lanes alias g-2 (values inert)
    const char* ap = smem + SC_OFF + (size_t)col * 16 + (g & 1) * 8;
    const uint32_t vg4 = (uint32_t)(g << 2);
    const int hb = half * 512;

    uint32_t A[16], P[16];
    #pragma unroll
    for (int chain = 0; chain < 2; ++chain) {
        uint32_t* D = chain ? P : A;
        #pragma unroll
        for (int t = 0; t < 16; ++t) {
            const int tb = hb + chain * 256 + t * 16;
            const long a = *(const long*)(ap + (size_t)tb * 16);
            const f32x4 sq = *(const f32x4*)(ssq + tb + g * 4);
            // acc[v] = 128 + |c|^2 - 2<c~,q~>, cand = tb + 4g + v (one quad)
            f32x4 acc = __builtin_amdgcn_mfma_f32_16x16x32_fp8_fp8(a, bfrag, sq, 0, 0, 0);
            const uint32_t ib = (uint32_t)tb + vg4;
            uint32_t k0 = (__float_as_uint(acc[0]) & 0xFFFFFC00u) | ib;
            uint32_t k1 = (__float_as_uint(acc[1]) & 0xFFFFFC00u) | (ib + 1u);
            uint32_t k2 = (__float_as_uint(acc[2]) & 0xFFFFFC00u) | (ib + 2u);
            uint32_t k3 = (__float_as_uint(acc[3]) & 0xFFFFFC00u) | (ib + 3u);
            D[t] = umn(umn(k0, k1), umn(k2, k3));
        }
        sort16(D);
    }
    keep16(A, P);
    mergeg(A);  // all 4 g-lanes: identical sorted top-16 quad-mins of this half

    // ---- cross-half merge; merge buffer overlays the norm region ----
    uint32_t* sm = (uint32_t*)(smem + SMG_OFF);
    __syncthreads();                  // everyone done reading coords/norms
    if (half == 1) {
        #pragma unroll
        for (int v = 0; v < 4; ++v) sm[qloc * 16 + g * 4 + v] = sel4(A, g, v);
    }
    __syncthreads();
    if (half == 1) return;

    {
        uint32_t Q[16];
        #pragma unroll
        for (int i = 0; i < 16; ++i) Q[i] = sm[qloc * 16 + i];
        keep16(A, Q);
    }

    // winners: lane g owns A[4g..4g+3]; stash full A to LDS (frees regs in repair)
    uint32_t win[4];
    #pragma unroll
    for (int v = 0; v < 4; ++v) {
        win[v] = sel4(A, g, v);
        sm[qloc * 16 + g * 4 + v] = win[v];   // wave-lockstep write, read back later
    }

    // ---- repair: 3 quad-partners per winner, f32 from global, fused norm ----
    const f32x4* qr = gx4 + (size_t)(qbase + qloc) * 4;
    const f32x4 qf0 = qr[0], qf1 = qr[1], qf2 = qr[2], qf3 = qr[3];
    uint32_t R[16];
    #pragma unroll
    for (int v = 0; v < 4; ++v) {
        const uint32_t wi  = win[v] & 1023u;
        const uint32_t qb2 = wi & ~3u;
        const uint32_t wo  = wi & 3u;
        #pragma unroll
        for (int k = 0; k < 3; ++k) {
            const uint32_t o    = (uint32_t)k + (((uint32_t)k >= wo) ? 1u : 0u);
            const uint32_t pidx = qb2 + o;
            const f32x4* cr = gx4 + (size_t)pidx * 4;
            float s = 128.0f;
            #pragma unroll
            for (int d = 0; d < 4; ++d) {
                f32x4 cv = cr[d];
                f32x4 qv = (d == 0) ? qf0 : (d == 1) ? qf1 : (d == 2) ? qf2 : qf3;
                #pragma unroll
                for (int e = 0; e < 4; ++e) {
                    float t = __builtin_fmaf(qv[e], -2.0f, cv[e]);  // c - 2q
                    s = __builtin_fmaf(cv[e], t, s);                // += c*(c-2q)
                }
            }
            R[v * 3 + k] = (__float_as_uint(s) & 0xFFFFFC00u) | pidx;
        }
    }
    #pragma unroll
    for (int i = 12; i < 16; ++i) R[i] = 0xFFFFFFFFu;
    sort16(R);
    mergeg(R);       // 48 partners across g-lanes -> lowest 16, all lanes equal

    // reload winners (A) and final keep-16
    uint32_t A2[16];
    #pragma unroll
    for (int i = 0; i < 16; ++i) A2[i] = sm[qloc * 16 + i];
    keep16(A2, R);

    // ---- epilogue: lane (g,col) writes int4 #g of src and dst ----
    const int base = seg * L_SEG;
    const int q    = qglob;
    int4 sv;
    sv.x = base + (int)(sel4(A2, g, 0) & 1023u);
    sv.y = base + (int)(sel4(A2, g, 1) & 1023u);
    sv.z = base + (int)(sel4(A2, g, 2) & 1023u);
    sv.w = base + (int)(sel4(A2, g, 3) & 1023u);
    ((int4*)out)[(size_t)q * 4 + g] = sv;
    ((int4*)out)[(size_t)M_PTS * 4 + (size_t)q * 4 + g] = make_int4(q, q, q, q);
}

extern "C" void kernel_launch(void* const* d_in, const int* in_sizes, int n_in,
                              void* d_out, int out_size, void* d_ws, size_t ws_size,
                              hipStream_t stream) {
    const float* x = (const float*)d_in[0];
    // d_in[1] = segs (int64, all 1024) — static per problem setup, unused.
    int* out = (int*)d_out;
    (void)d_ws; (void)ws_size;
    knn_v13_kernel<<<dim3(2048), dim3(256), 0, stream>>>(x, out);
}